// Round 5
// baseline (18.832 us; speedup 1.0000x reference)
//
#include <hip/hip_runtime.h>
#include <math.h>

// Problem constants (from reference): N=32, CI=32, CO=32, H=64, W=64, K=2
#define NN 32
#define CI 32
#define CO 32
#define HH 64
#define WW 64

#define G    4            // co's per thread
#define COG  (CO / G)     // 8 co-groups
#define NXCD 8

typedef float v4f __attribute__((ext_vector_type(4)));   // native vec for NT stores

// ---------------------------------------------------------------------------
// out[n,co,h,w] = log( sum_ci W[co,ci,par(h,w)] * exp(x[n,ci,h,w]) ),
//   W = softmax(logits over ci), par = (h&1)*2 + (w&1).
//
// R4 post-mortem: weight-fetch instruction count (1 fetch : 4 FMAs) was the
// bottleneck (~10us on the LDS/VMEM pipe regardless of path). Fix: each
// thread owns a 4x4 PIXEL TILE so one float4 weight read feeds 16 FMAs.
//
// Geometry: 256 blocks x 256 threads. Block = (image n, co-group cog).
//   wave w covers rows [w*16, w*16+16), lane: (lane>>4) = h-band, (lane&15)
//   = w-tile -> float4 x loads are fully coalesced (lanes 0-15 contiguous).
// XCD swizzle: XCD k owns images 4k..4k+3 for ALL 8 co-groups -> 2 MB x slab
// stays L2-resident across the 8x logical re-read. NT stores keep the out
// stream from evicting it. 1 block/CU, 4 waves, 1 wave/SIMD (ILP hides lat).
// ---------------------------------------------------------------------------
__global__ __launch_bounds__(256) void sumconv_fused(
        const float* __restrict__ x,
        const float* __restrict__ logits,
        float* __restrict__ out) {
    const int b    = blockIdx.x;          // 0..255
    const int xcd  = b & (NXCD - 1);
    const int s    = b >> 3;              // 0..31
    const int n    = xcd * 4 + (s & 3);   // image
    const int cog  = s >> 2;              // 0..7
    const int co_base = cog * G;

    __shared__ float4 WF[G * CI];         // [j][ci] -> float4 over parities

    // ---- Phase 0: per-block weight softmax (16 active threads) ----
    const int t = threadIdx.x;
    if (t < G * 4) {
        const int j   = t >> 2;           // local co
        const int par = t & 3;
        const float* base = logits + (co_base + j) * CI * 4 + par;

        float m = -1e30f;
#pragma unroll
        for (int ci = 0; ci < CI; ++ci) m = fmaxf(m, base[ci * 4]);

        float e[CI];
        float ssum = 0.0f;
#pragma unroll
        for (int ci = 0; ci < CI; ++ci) {
            e[ci] = __expf(base[ci * 4] - m);
            ssum += e[ci];
        }
        const float inv = 1.0f / ssum;
#pragma unroll
        for (int ci = 0; ci < CI; ++ci)
            ((float*)&WF[j * CI + ci])[par] = e[ci] * inv;
    }
    __syncthreads();

    // ---- Phase 1: 4x4 pixel tile accumulation ----
    const int lane  = t & 63;
    const int wv_id = t >> 6;                       // wave in block, 0..3
    const int h0 = wv_id * 16 + (lane >> 4) * 4;    // tile top row (even)
    const int w0 = (lane & 15) * 4;                 // tile left col (even)

    const float* xb = x + ((n * CI) * HH + h0) * WW + w0;

    float acc[4][4][G];                   // [row][col][co]
#pragma unroll
    for (int r = 0; r < 4; ++r)
#pragma unroll
        for (int c = 0; c < 4; ++c)
#pragma unroll
            for (int j = 0; j < G; ++j) acc[r][c][j] = 0.0f;

#pragma unroll 2
    for (int ci = 0; ci < CI; ++ci) {
        const float* xr = xb + ci * (HH * WW);
        float e[4][4];
#pragma unroll
        for (int r = 0; r < 4; ++r) {
            const float4 v = *(const float4*)(xr + r * WW);
            e[r][0] = __expf(v.x);
            e[r][1] = __expf(v.y);
            e[r][2] = __expf(v.z);
            e[r][3] = __expf(v.w);
        }
#pragma unroll
        for (int j = 0; j < G; ++j) {
            const float4 wv = WF[j * CI + ci];      // 1 fetch : 16 FMAs
#pragma unroll
            for (int r = 0; r < 4; ++r) {
                const float wlo = (r & 1) ? wv.z : wv.x;   // even col parity
                const float whi = (r & 1) ? wv.w : wv.y;   // odd  col parity
                acc[r][0][j] = fmaf(wlo, e[r][0], acc[r][0][j]);
                acc[r][1][j] = fmaf(whi, e[r][1], acc[r][1][j]);
                acc[r][2][j] = fmaf(wlo, e[r][2], acc[r][2][j]);
                acc[r][3][j] = fmaf(whi, e[r][3], acc[r][3][j]);
            }
        }
    }

    // ---- Epilogue: log + NT store (float4 per row per co) ----
#pragma unroll
    for (int j = 0; j < G; ++j) {
        const int co = co_base + j;
        float* ob = out + ((n * CO + co) * HH + h0) * WW + w0;
#pragma unroll
        for (int r = 0; r < 4; ++r) {
            v4f o;
            o.x = __logf(acc[r][0][j]);
            o.y = __logf(acc[r][1][j]);
            o.z = __logf(acc[r][2][j]);
            o.w = __logf(acc[r][3][j]);
            __builtin_nontemporal_store(o, (v4f*)(ob + r * WW));
        }
    }
}

extern "C" void kernel_launch(void* const* d_in, const int* in_sizes, int n_in,
                              void* d_out, int out_size, void* d_ws, size_t ws_size,
                              hipStream_t stream) {
    const float* x      = (const float*)d_in[0];
    const float* logits = (const float*)d_in[1];
    float* out = (float*)d_out;

    sumconv_fused<<<NN * COG, 256, 0, stream>>>(x, logits, out);
}

// Round 6
// 17.639 us; speedup vs baseline: 1.0676x; 1.0676x over previous
//
#include <hip/hip_runtime.h>
#include <math.h>

// Problem constants (from reference): N=32, CI=32, CO=32, H=64, W=64, K=2
#define NN 32
#define CI 32
#define CO 32
#define HH 64
#define WW 64

#define G    4            // co's per thread
#define COG  (CO / G)     // 8 co-groups
#define NXCD 8

typedef float v2f __attribute__((ext_vector_type(2)));   // native vec for NT stores

// ---------------------------------------------------------------------------
// out[n,co,h,w] = log( sum_ci W[co,ci,par(h,w)] * exp(x[n,ci,h,w]) ),
//   W = softmax(logits over ci), par = (h&1)*2 + (w&1).
//
// R5 post-mortem: kernel is latency-bound (VALUBusy 13%, occupancy 9%, HBM
// 7%): 1 wave/SIMD + VGPR-pressure (acc=64) killed both TLP and MLP; every
// ci-iter ate a full memory latency. Fix:
//   - 2x2 quad per thread, G=4 -> acc=16 regs, small working set
//   - 1024 blocks (4/CU) -> 16 waves/CU (occupancy 9% -> ~37%)
//   - explicit distance-2 prefetch -> 4 x-loads always in flight
//
// XCD swizzle: xcd = b&7 owns images [4*xcd, 4*xcd+4) for all 8 co-groups
// and all 4 image-quarters (128 blocks/XCD, all co-resident) -> 2 MB x slab
// L2-resident across the 8x logical re-read. NT stores protect the slab.
// ---------------------------------------------------------------------------
__global__ __launch_bounds__(256, 4) void sumconv_fused(
        const float* __restrict__ x,
        const float* __restrict__ logits,
        float* __restrict__ out) {
    const int b    = blockIdx.x;          // 0..1023
    const int xcd  = b & (NXCD - 1);
    const int s    = b >> 3;              // 0..127
    const int n    = xcd * 4 + (s & 3);   // image
    const int cog  = (s >> 2) & 7;        // 0..7
    const int quarter = s >> 5;           // 0..3
    const int co_base = cog * G;

    __shared__ float4 WF[G * CI];         // [j][ci] -> float4 over parities (2 KB)

    // ---- Phase 0: per-block weight softmax (16 active threads) ----
    const int t = threadIdx.x;
    if (t < G * 4) {
        const int j   = t >> 2;           // local co
        const int par = t & 3;
        const float* base = logits + (co_base + j) * CI * 4 + par;

        float m = -1e30f;
#pragma unroll
        for (int ci = 0; ci < CI; ++ci) m = fmaxf(m, base[ci * 4]);

        float e[CI];
        float ssum = 0.0f;
#pragma unroll
        for (int ci = 0; ci < CI; ++ci) {
            e[ci] = __expf(base[ci * 4] - m);
            ssum += e[ci];
        }
        const float inv = 1.0f / ssum;
#pragma unroll
        for (int ci = 0; ci < CI; ++ci)
            ((float*)&WF[j * CI + ci])[par] = e[ci] * inv;
    }
    __syncthreads();

    // ---- Phase 1: 2x2 quad accumulation, distance-2 prefetch ----
    const int q  = quarter * 256 + t;               // quad id in image, 0..1023
    const int h0 = (q >> 5) << 1;                   // even row
    const int w0 = (q & 31) << 1;                   // even col

    const float* xb = x + ((n * CI) * HH + h0) * WW + w0;
    const int plane = HH * WW;

    float acc[4][G];
#pragma unroll
    for (int p = 0; p < 4; ++p)
#pragma unroll
        for (int j = 0; j < G; ++j) acc[p][j] = 0.0f;

    // prefetch pipeline: 2 ci-planes in flight (4 loads)
    float2 c0a = *(const float2*)(xb);
    float2 c0b = *(const float2*)(xb + WW);
    float2 c1a = *(const float2*)(xb + plane);
    float2 c1b = *(const float2*)(xb + plane + WW);

#pragma unroll
    for (int ci = 0; ci < CI; ++ci) {
        const float2 va = c0a;
        const float2 vb = c0b;
        c0a = c1a; c0b = c1b;
        if (ci + 2 < CI) {
            c1a = *(const float2*)(xb + (ci + 2) * plane);
            c1b = *(const float2*)(xb + (ci + 2) * plane + WW);
        }
        const float e00 = __expf(va.x);
        const float e01 = __expf(va.y);
        const float e10 = __expf(vb.x);
        const float e11 = __expf(vb.y);
#pragma unroll
        for (int j = 0; j < G; ++j) {
            const float4 wv = WF[j * CI + ci];      // uniform addr -> broadcast
            acc[0][j] = fmaf(wv.x, e00, acc[0][j]);
            acc[1][j] = fmaf(wv.y, e01, acc[1][j]);
            acc[2][j] = fmaf(wv.z, e10, acc[2][j]);
            acc[3][j] = fmaf(wv.w, e11, acc[3][j]);
        }
    }

    // ---- Epilogue: log + NT store ----
#pragma unroll
    for (int j = 0; j < G; ++j) {
        const int co = co_base + j;
        float* ob = out + ((n * CO + co) * HH + h0) * WW + w0;
        v2f r0, r1;
        r0.x = __logf(acc[0][j]);
        r0.y = __logf(acc[1][j]);
        r1.x = __logf(acc[2][j]);
        r1.y = __logf(acc[3][j]);
        __builtin_nontemporal_store(r0, (v2f*)ob);
        __builtin_nontemporal_store(r1, (v2f*)(ob + WW));
    }
}

extern "C" void kernel_launch(void* const* d_in, const int* in_sizes, int n_in,
                              void* d_out, int out_size, void* d_ws, size_t ws_size,
                              hipStream_t stream) {
    const float* x      = (const float*)d_in[0];
    const float* logits = (const float*)d_in[1];
    float* out = (float*)d_out;

    sumconv_fused<<<NN * COG * 4, 256, 0, stream>>>(x, logits, out);
}

// Round 7
// 14.374 us; speedup vs baseline: 1.3101x; 1.2271x over previous
//
#include <hip/hip_runtime.h>
#include <math.h>

// Problem constants: N=32, CI=32, CO=32, H=64, W=64, K=2
#define NN 32
#define CI 32
#define CO 32
#define HH 64
#define WW 64

typedef __attribute__((ext_vector_type(8))) short bf16x8;   // MFMA A/B frag (4 VGPR)
typedef __attribute__((ext_vector_type(4))) float f32x4;    // MFMA C/D frag

// float -> bf16 (round-to-nearest-even)
__device__ inline short f2bf(float f) {
    union { float f; unsigned u; } v; v.f = f;
    unsigned r = v.u + 0x7FFFu + ((v.u >> 16) & 1u);
    return (short)(r >> 16);
}

// ---------------------------------------------------------------------------
// out[n,co,h,w] = log( sum_ci W[co,ci,par] * exp(x[n,ci,h,w]) ),
//   W = softmax(logits over ci), par = (h&1)*2 + (w&1).
//
// R6 post-mortem: the VALU structure's CO-split (COG=8) multiplies every
// pipe cost 8x (x re-read, exp recompute, 33M weight fetches); no knob on
// that structure moved the needle. MFMA removes the split: per parity this
// is a 32x32xK32 GEMM -> ONE mfma_f32_16x16x32_bf16 per (co-half, px-tile).
//
// Block = (image n, row-pair r): 1024 blocks x 256 threads.
//   Phase 0: softmax weights -> LDS Wl[par][co][ci] (16 KB, once).
//   Wave w = parity (pr=w>>1, pc=w&1), owns row h=2r+pr, cols pc,pc+2,...
//     A-frags (2): W[co=lane&15 +16t][ci=(lane>>4)*8+i]  (loaded ONCE)
//     B-frags (2): exp(x[ci][w=2*(lane&15+16u)+pc]) -> bf16
//     acc[t][u] = mfma(A[t], B[u], 0)   -- 4 MFMAs total, K=32 in one shot
//   Store: co = 16t + 4*(lane>>4) + reg, w as above. Parity-pair waves write
//   complementary stride-2 dwords of the same lines -> L2 write-combines
//   (normal stores, NOT nontemporal, so merging happens in L2).
//
// x is read ONCE (no co-split), exp computed once per element (4.2M not 34M),
// weights fetched once per wave. Expect HBM-bound: ~33 MB @ 6.3 TB/s.
// ---------------------------------------------------------------------------
__global__ __launch_bounds__(256, 4) void sumconv_mfma(
        const float* __restrict__ x,
        const float* __restrict__ logits,
        float* __restrict__ out) {
    const int b   = blockIdx.x;           // 0..1023
    const int xcd = b & 7;
    const int s   = b >> 3;               // 0..127
    const int n   = xcd * 4 + (s & 3);    // image (XCD-chunked for L2)
    const int r   = s >> 2;               // row-pair 0..31

    __shared__ float Wl[4][CO][CI];       // [par][co][ci], 16 KB

    // ---- Phase 0: softmax weights into LDS (128 active threads) ----
    const int t = threadIdx.x;
    if (t < 128) {
        const int co = t >> 2, par = t & 3;
        const float* base = logits + (co * CI) * 4 + par;
        float m = -1e30f;
#pragma unroll
        for (int ci = 0; ci < CI; ++ci) m = fmaxf(m, base[ci * 4]);
        float e[CI]; float ssum = 0.0f;
#pragma unroll
        for (int ci = 0; ci < CI; ++ci) { e[ci] = __expf(base[ci * 4] - m); ssum += e[ci]; }
        const float inv = 1.0f / ssum;
#pragma unroll
        for (int ci = 0; ci < CI; ++ci) Wl[par][co][ci] = e[ci] * inv;
    }
    __syncthreads();

    const int wave = t >> 6;              // 0..3 = parity
    const int lane = t & 63;
    const int pr = wave >> 1, pc = wave & 1;
    const int l15 = lane & 15, kb = lane >> 4;

    // ---- A-frags: A[row=co][k=ci], row=l15+16t, k=kb*8+i (k-perm arbitrary,
    //      but IDENTICAL indexing used for B -> contraction invariant) ----
    bf16x8 afr[2];
#pragma unroll
    for (int tt = 0; tt < 2; ++tt) {
        const float* wp = &Wl[wave][l15 + 16 * tt][kb * 8];
#pragma unroll
        for (int i = 0; i < 8; ++i) afr[tt][i] = f2bf(wp[i]);
    }

    // ---- B-frags: B[k=ci][col=j], j=l15+16u -> w=2*j+pc, ci=kb*8+i ----
    const int h = 2 * r + pr;
    const float* xb = x + ((n * CI) * HH + h) * WW;   // + ci*HH*WW + w
    bf16x8 bfr[2];
#pragma unroll
    for (int u = 0; u < 2; ++u) {
        const int wcol = 2 * (l15 + 16 * u) + pc;
        const float* xp = xb + (kb * 8) * (HH * WW) + wcol;
        float ev[8];
#pragma unroll
        for (int i = 0; i < 8; ++i) ev[i] = xp[i * (HH * WW)];   // 8 loads issue together
#pragma unroll
        for (int i = 0; i < 8; ++i) bfr[u][i] = f2bf(__expf(ev[i]));
    }

    // ---- 4 MFMAs: D[16co x 16px], K=32 ----
    f32x4 acc[2][2];
#pragma unroll
    for (int tt = 0; tt < 2; ++tt)
#pragma unroll
        for (int u = 0; u < 2; ++u)
            acc[tt][u] = __builtin_amdgcn_mfma_f32_16x16x32_bf16(
                afr[tt], bfr[u], (f32x4){0.f, 0.f, 0.f, 0.f}, 0, 0, 0);

    // ---- Epilogue: log + store. D: col=l15, row=4*kb+reg (HW-verified) ----
#pragma unroll
    for (int tt = 0; tt < 2; ++tt) {
#pragma unroll
        for (int u = 0; u < 2; ++u) {
            const int wcol = 2 * (l15 + 16 * u) + pc;
#pragma unroll
            for (int reg = 0; reg < 4; ++reg) {
                const int co = 16 * tt + 4 * kb + reg;
                out[((n * CO + co) * HH + h) * WW + wcol] = __logf(acc[tt][u][reg]);
            }
        }
    }
}

extern "C" void kernel_launch(void* const* d_in, const int* in_sizes, int n_in,
                              void* d_out, int out_size, void* d_ws, size_t ws_size,
                              hipStream_t stream) {
    const float* x      = (const float*)d_in[0];
    const float* logits = (const float*)d_in[1];
    float* out = (float*)d_out;

    sumconv_mfma<<<NN * (HH / 2), 256, 0, stream>>>(x, logits, out);
}